// Round 21
// baseline (148.041 us; speedup 1.0000x reference)
//
#include <hip/hip_runtime.h>

// LSTM (B=8192, T=256, in=1, H=64) + fc1(64->32,relu) + fc2(32->2).
// R19 frame + x-float4-preload (NO setprio -- A/B isolation of R20's bundle).
// 512 blocks x 512 thr (8 waves) = 2 blocks/CU -> 4 waves/SIMD, 2 cells/lane.
// Wave w owns tiles 2w,2w+1 (consecutive-unit permutation); lane's cells =
// units (8w+2*l4,+1) -> one packed ds_write_b32. Barrier-shadow hoist:
// next-step acc-init before the barrier, MFMA consumes init as C. Packed-fp32
// (v_pk_*) cell math. x read as one ds_read_b128 per 4 steps (carried xq;
// next group's read issued 1.5 steps early; XPAD covers tail over-read).
// h: fp16 plane [16][64], 128B rows, 16B-block XOR swizzle (blk ^= row&7).
// Cell: common-denominator, 5 exp2 + 2 rcp.

typedef __attribute__((ext_vector_type(8))) _Float16 f16x8;
typedef __attribute__((ext_vector_type(4))) float f32x4;
typedef __attribute__((ext_vector_type(2))) float f32x2;

#define TT 256
#define BT 16
#define XPAD 260

#if __has_builtin(__builtin_amdgcn_exp2f)
#define EXP2F __builtin_amdgcn_exp2f
#else
#define EXP2F exp2f
#endif
#if __has_builtin(__builtin_amdgcn_rcpf)
#define RCPF __builtin_amdgcn_rcpf
#else
#define RCPF(x) (1.0f / (x))
#endif
#if __has_builtin(__builtin_amdgcn_fmed3f)
#define MED3F __builtin_amdgcn_fmed3f
#else
#define MED3F(a, lo, hi) fminf(fmaxf((a), (lo)), (hi))
#endif

#define NLOG2E  -1.4426950408889634f
#define N2LOG2E -2.8853900817779268f

__device__ __forceinline__ float h2f(ushort u) {
    union { ushort u; _Float16 h; } v;
    v.u = u;
    return (float)v.h;
}
__device__ __forceinline__ unsigned pack2h(float a, float b) {  // RNE f32->f16 x2
    union { _Float16 h[2]; unsigned u; } v;
    v.h[0] = (_Float16)a;
    v.h[1] = (_Float16)b;
    return v.u;
}

__global__ __launch_bounds__(512, 4) void lstm_x4b(
    const float* __restrict__ x,      // [B,T]
    const float* __restrict__ W_ih,   // [256]
    const float* __restrict__ W_hh,   // [256][64]
    const float* __restrict__ b_ih,   // [256]
    const float* __restrict__ b_hh,   // [256]
    const float* __restrict__ fc1_w,  // [32][64]
    const float* __restrict__ fc1_b,  // [32]
    const float* __restrict__ fc2_w,  // [2][32]
    const float* __restrict__ fc2_b,  // [2]
    float* __restrict__ out)          // [B][2]
{
    __shared__ float  x_lds[BT][XPAD];
    __shared__ ushort h_pl[2][BT * 64];   // fp16, 128B rows, XOR-swizzled 16B blocks

    const int tid  = threadIdx.x;
    const int lane = tid & 63;
    const int w    = tid >> 6;       // wave 0..7 -> tiles 2w, 2w+1
    const int l15  = lane & 15;      // batch (C col / B-frag n); A-frag row m
    const int l4   = lane >> 4;      // 0..3
    const int s7   = l15 & 7;        // swizzle key (row)
    const long long bBase = (long long)blockIdx.x * BT;

    // ---- stage x tile: 1024 float4s / 512 thr ----
    {
        const float4* xg = (const float4*)(x + bBase * TT);
        for (int i = tid; i < BT * TT / 4; i += 512) {
            int b = i >> 6, c4 = i & 63;
            *(float4*)&x_lds[b][c4 * 4] = xg[i];
        }
    }
    // ---- zero h buffer 0: 2048 ushorts = 512 x 8B ----
    ((unsigned long long*)h_pl[0])[tid] = 0ull;

    // ---- A-frags: W_hh unit-major permuted rows, fp16, pre-scaled ----
    // Tile tt, lane row m=l15 -> unit = 8w + 2*(m>>2) + tt, gate = m&3;
    // k = kt*32 + l4*8 + j.  (Consecutive-unit permutation.)
    const int gateA = l15 & 3;
    const float sgA = (gateA == 2) ? N2LOG2E : NLOG2E;
    f16x8 Af[2][2];
#pragma unroll
    for (int tt = 0; tt < 2; ++tt) {
        const int unit = 8 * w + 2 * (l15 >> 2) + tt;
#pragma unroll
        for (int kt = 0; kt < 2; ++kt) {
            const float* src = W_hh + (gateA * 64 + unit) * 64 + kt * 32 + l4 * 8;
#pragma unroll
            for (int j = 0; j < 8; ++j)
                Af[tt][kt][j] = (_Float16)(src[j] * sgA);
        }
    }

    // ---- per-lane cell params: cell tt -> (batch l15, unit = 8w+2*l4+tt) ----
    float wih[2][4], bias[2][4];
#pragma unroll
    for (int tt = 0; tt < 2; ++tt) {
        const int u = 8 * w + 2 * l4 + tt;
#pragma unroll
        for (int g = 0; g < 4; ++g) {
            const float sg = (g == 2) ? N2LOG2E : NLOG2E;
            const int idx = g * 64 + u;
            wih[tt][g]  = W_ih[idx] * sg;
            bias[tt][g] = (b_ih[idx] + b_hh[idx]) * sg;
        }
    }

    // ---- swizzled LDS offsets (ushort units), loop-invariant ----
    const int ro  = l15 * 64;                       // row base
    const int rd0 = ro + ((l4 ^ s7) << 3);          // k-frag 0 (k=0..31)
    const int rd1 = ro + (((4 + l4) ^ s7) << 3);    // k-frag 1 (k=32..63)
    // write: units (8w+2*l4, +1) -> block w (^s7), offset 2*l4; one u32
    const int wo2 = ro + ((w ^ s7) << 3) + 2 * l4;  // even ushort index

    f32x2 cst2 = {0.0f, 0.0f};   // c-state for (cell0, cell1), packed

    // ---- first-step init (hoisted pattern); xq = x[l15][0..3] ----
    f32x4 accI[2];
    float4 xq;
    __syncthreads();
    xq = *(const float4*)&x_lds[l15][0];
#pragma unroll
    for (int tt = 0; tt < 2; ++tt)
#pragma unroll
        for (int g = 0; g < 4; ++g)
            accI[tt][g] = xq.x * wih[tt][g] + bias[tt][g];

    // one LSTM step at compile-time-constant buffer p; xn = x for NEXT step.
    // accI enters holding this step's init (C operand) and leaves holding
    // next step's init (computed in the barrier shadow).
    auto stepf = [&](int p, float xn) {
        const f16x8 B0 = *(const f16x8*)&h_pl[p][rd0];
        const f16x8 B1 = *(const f16x8*)&h_pl[p][rd1];

        f32x4 a0 = __builtin_amdgcn_mfma_f32_16x16x32_f16(Af[0][0], B0, accI[0], 0, 0, 0);
        f32x4 a1 = __builtin_amdgcn_mfma_f32_16x16x32_f16(Af[1][0], B0, accI[1], 0, 0, 0);
        a0 = __builtin_amdgcn_mfma_f32_16x16x32_f16(Af[0][1], B1, a0, 0, 0, 0);
        a1 = __builtin_amdgcn_mfma_f32_16x16x32_f16(Af[1][1], B1, a1, 0, 0, 0);

        // next-step acc init (independent; fills the pre-barrier shadow)
#pragma unroll
        for (int tt = 0; tt < 2; ++tt)
#pragma unroll
            for (int g = 0; g < 4; ++g)
                accI[tt][g] = xn * wih[tt][g] + bias[tt][g];

        // two cell chains PAIRED component-wise (x = cell0, y = cell1);
        // elementwise ops lower to v_pk_{add,mul,fma}_f32. (i,f,g,o pre-scaled)
        // A=e^-pi F=e^-pf B=e^-2pg C=e^-po
        // cc = [c(1+A)(1+B) + (1-B)(1+F)] / [(1+F)(1+A)(1+B)]
        // hn = (1-D)/[(1+C)(1+D)],  D = e^-2cc
        f32x2 eA, eF, eB, eC;
        eA.x = EXP2F(a0[0]); eA.y = EXP2F(a1[0]);
        eF.x = EXP2F(a0[1]); eF.y = EXP2F(a1[1]);
        eB.x = EXP2F(a0[2]); eB.y = EXP2F(a1[2]);
        eC.x = EXP2F(a0[3]); eC.y = EXP2F(a1[3]);

        const f32x2 pA = eA + 1.0f;
        const f32x2 pF = eF + 1.0f;
        const f32x2 pB = eB + 1.0f;
        const f32x2 pC = eC + 1.0f;
        const f32x2 P   = pA * pB;
        const f32x2 den = P * pF;
        const f32x2 tmb = (1.0f - eB) * pF;
        const f32x2 num = cst2 * P + tmb;
        f32x2 rden;
        rden.x = RCPF(den.x); rden.y = RCPF(den.y);
        const f32x2 cc = num * rden;
        cst2 = cc;
        f32x2 targ = cc * N2LOG2E;
        targ.x = MED3F(targ.x, -60.0f, 60.0f);   // avoid Inf/Inf -> NaN
        targ.y = MED3F(targ.y, -60.0f, 60.0f);
        f32x2 D;
        D.x = EXP2F(targ.x); D.y = EXP2F(targ.y);
        const f32x2 omD  = 1.0f - D;
        const f32x2 prod = pC * (1.0f + D);
        f32x2 rp;
        rp.x = RCPF(prod.x); rp.y = RCPF(prod.y);
        const f32x2 hn2 = omD * rp;

        // packed RNE fp16 pair -> one ds_write_b32 (consecutive units)
        *(unsigned*)&h_pl[p ^ 1][wo2] = pack2h(hn2.x, hn2.y);

        __syncthreads();
    };

    // 4 steps per iteration; one ds_read_b128 of x per group, issued 1.5
    // steps before first use. Final group reads [256..259] = row padding
    // (allocated, value unused -- feeds the never-consumed accI of t=256).
#pragma unroll 1
    for (int t = 0; t < TT; t += 4) {
        stepf(0, xq.y);                                       // step t
        stepf(1, xq.z);                                       // step t+1
        const float4 xq2 = *(const float4*)&x_lds[l15][t + 4];
        stepf(0, xq.w);                                       // step t+2
        stepf(1, xq2.x);                                      // step t+3
        xq = xq2;
    }
    // final h is in buffer 0

    // ---- tail: fc1 + relu into x_lds (x dead), then fc2 ----
    {
        const int b = tid >> 5, u2 = tid & 31;   // 512 = 16 x 32
        float a = fc1_b[u2];
        for (int k = 0; k < 64; ++k) {
            const int off = b * 64 + ((((k >> 3) ^ (b & 7))) << 3) + (k & 7);
            a += fc1_w[u2 * 64 + k] * h2f(h_pl[0][off]);
        }
        x_lds[b][u2] = a > 0.0f ? a : 0.0f;
    }
    __syncthreads();
    if (tid < BT * 2) {
        const int b = tid >> 1, o = tid & 1;
        float a = fc2_b[o];
#pragma unroll
        for (int u2 = 0; u2 < 32; ++u2)
            a += x_lds[b][u2] * fc2_w[o * 32 + u2];
        out[(bBase + b) * 2 + o] = a;
    }
}

extern "C" void kernel_launch(void* const* d_in, const int* in_sizes, int n_in,
                              void* d_out, int out_size, void* d_ws, size_t ws_size,
                              hipStream_t stream) {
    const float* x     = (const float*)d_in[0];
    const float* W_ih  = (const float*)d_in[1];
    const float* W_hh  = (const float*)d_in[2];
    const float* b_ih  = (const float*)d_in[3];
    const float* b_hh  = (const float*)d_in[4];
    const float* fc1_w = (const float*)d_in[5];
    const float* fc1_b = (const float*)d_in[6];
    const float* fc2_w = (const float*)d_in[7];
    const float* fc2_b = (const float*)d_in[8];
    float* out = (float*)d_out;

    lstm_x4b<<<dim3(8192 / BT), dim3(512), 0, stream>>>(
        x, W_ih, W_hh, b_ih, b_hh, fc1_w, fc1_b, fc2_w, fc2_b, out);
}

// Round 22
// 145.761 us; speedup vs baseline: 1.0156x; 1.0156x over previous
//
#include <hip/hip_runtime.h>

// LSTM (B=8192, T=256, in=1, H=64) + fc1(64->32,relu) + fc2(32->2).
// FINAL (= R19 best, 145.9 us): packed-FP32 (VOPP) cell math on the R18
// frame. 512 blocks x 512 thr (8 waves) = 2 blocks/CU -> 4 waves/SIMD,
// 2 cells/lane. Wave w owns tiles 2w,2w+1 (consecutive-unit permutation:
// tile tt = units {8w+2U+tt}); lane's cells = units (8w+2*l4,+1) -> one
// packed ds_write_b32. Barrier-shadow hoist: next-x read + acc-init before
// the barrier, MFMA consumes init as C. Two cell chains paired
// component-wise in float2 -> v_pk_{add,mul,fma}_f32. h: fp16 plane
// [16][64], 128B rows, 16B-block XOR swizzle (blk ^= row&7). Cell:
// common-denominator form, 5 exp2 + 2 rcp per cell.
// A/B-verified neutral/negative and EXCLUDED: setprio role-split (R20),
// x-float4 preload (R21), anti-phase stagger (R13), 4 barrier groups (R11),
// in-wave dual chain (R14), 32x32 retile (R10).

typedef __attribute__((ext_vector_type(8))) _Float16 f16x8;
typedef __attribute__((ext_vector_type(4))) float f32x4;
typedef __attribute__((ext_vector_type(2))) float f32x2;

#define TT 256
#define BT 16
#define XPAD 260

#if __has_builtin(__builtin_amdgcn_exp2f)
#define EXP2F __builtin_amdgcn_exp2f
#else
#define EXP2F exp2f
#endif
#if __has_builtin(__builtin_amdgcn_rcpf)
#define RCPF __builtin_amdgcn_rcpf
#else
#define RCPF(x) (1.0f / (x))
#endif
#if __has_builtin(__builtin_amdgcn_fmed3f)
#define MED3F __builtin_amdgcn_fmed3f
#else
#define MED3F(a, lo, hi) fminf(fmaxf((a), (lo)), (hi))
#endif

#define NLOG2E  -1.4426950408889634f
#define N2LOG2E -2.8853900817779268f

__device__ __forceinline__ float h2f(ushort u) {
    union { ushort u; _Float16 h; } v;
    v.u = u;
    return (float)v.h;
}
__device__ __forceinline__ unsigned pack2h(float a, float b) {  // RNE f32->f16 x2
    union { _Float16 h[2]; unsigned u; } v;
    v.h[0] = (_Float16)a;
    v.h[1] = (_Float16)b;
    return v.u;
}

__global__ __launch_bounds__(512, 4) void lstm_pk(
    const float* __restrict__ x,      // [B,T]
    const float* __restrict__ W_ih,   // [256]
    const float* __restrict__ W_hh,   // [256][64]
    const float* __restrict__ b_ih,   // [256]
    const float* __restrict__ b_hh,   // [256]
    const float* __restrict__ fc1_w,  // [32][64]
    const float* __restrict__ fc1_b,  // [32]
    const float* __restrict__ fc2_w,  // [2][32]
    const float* __restrict__ fc2_b,  // [2]
    float* __restrict__ out)          // [B][2]
{
    __shared__ float  x_lds[BT][XPAD];
    __shared__ ushort h_pl[2][BT * 64];   // fp16, 128B rows, XOR-swizzled 16B blocks

    const int tid  = threadIdx.x;
    const int lane = tid & 63;
    const int w    = tid >> 6;       // wave 0..7 -> tiles 2w, 2w+1
    const int l15  = lane & 15;      // batch (C col / B-frag n); A-frag row m
    const int l4   = lane >> 4;      // 0..3
    const int s7   = l15 & 7;        // swizzle key (row)
    const long long bBase = (long long)blockIdx.x * BT;

    // ---- stage x tile: 1024 float4s / 512 thr ----
    {
        const float4* xg = (const float4*)(x + bBase * TT);
        for (int i = tid; i < BT * TT / 4; i += 512) {
            int b = i >> 6, c4 = i & 63;
            *(float4*)&x_lds[b][c4 * 4] = xg[i];
        }
    }
    // ---- zero h buffer 0: 2048 ushorts = 512 x 8B ----
    ((unsigned long long*)h_pl[0])[tid] = 0ull;

    // ---- A-frags: W_hh unit-major permuted rows, fp16, pre-scaled ----
    // Tile tt, lane row m=l15 -> unit = 8w + 2*(m>>2) + tt, gate = m&3;
    // k = kt*32 + l4*8 + j.  (Consecutive-unit permutation.)
    const int gateA = l15 & 3;
    const float sgA = (gateA == 2) ? N2LOG2E : NLOG2E;
    f16x8 Af[2][2];
#pragma unroll
    for (int tt = 0; tt < 2; ++tt) {
        const int unit = 8 * w + 2 * (l15 >> 2) + tt;
#pragma unroll
        for (int kt = 0; kt < 2; ++kt) {
            const float* src = W_hh + (gateA * 64 + unit) * 64 + kt * 32 + l4 * 8;
#pragma unroll
            for (int j = 0; j < 8; ++j)
                Af[tt][kt][j] = (_Float16)(src[j] * sgA);
        }
    }

    // ---- per-lane cell params: cell tt -> (batch l15, unit = 8w+2*l4+tt) ----
    float wih[2][4], bias[2][4];
#pragma unroll
    for (int tt = 0; tt < 2; ++tt) {
        const int u = 8 * w + 2 * l4 + tt;
#pragma unroll
        for (int g = 0; g < 4; ++g) {
            const float sg = (g == 2) ? N2LOG2E : NLOG2E;
            const int idx = g * 64 + u;
            wih[tt][g]  = W_ih[idx] * sg;
            bias[tt][g] = (b_ih[idx] + b_hh[idx]) * sg;
        }
    }

    // ---- swizzled LDS offsets (ushort units), loop-invariant ----
    const int ro  = l15 * 64;                       // row base
    const int rd0 = ro + ((l4 ^ s7) << 3);          // k-frag 0 (k=0..31)
    const int rd1 = ro + (((4 + l4) ^ s7) << 3);    // k-frag 1 (k=32..63)
    // write: units (8w+2*l4, +1) -> block w (^s7), offset 2*l4; one u32
    const int wo2 = ro + ((w ^ s7) << 3) + 2 * l4;  // even ushort index

    f32x2 cst2 = {0.0f, 0.0f};   // c-state for (cell0, cell1), packed

    // ---- first-step init (hoisted pattern) ----
    f32x4 accI[2];
    __syncthreads();
    {
        const float xr = x_lds[l15][0];
#pragma unroll
        for (int tt = 0; tt < 2; ++tt)
#pragma unroll
            for (int g = 0; g < 4; ++g)
                accI[tt][g] = xr * wih[tt][g] + bias[tt][g];
    }

    // one LSTM step at compile-time-constant buffer p.
    // accI enters holding this step's init (C operand) and leaves holding
    // next step's init (computed in the barrier shadow).
    auto stepf = [&](int p, int t) {
        const f16x8 B0 = *(const f16x8*)&h_pl[p][rd0];
        const f16x8 B1 = *(const f16x8*)&h_pl[p][rd1];
        // hoisted next-x read (row pad makes t=255 over-read safe, value unused)
        const float xn = x_lds[l15][t + 1];

        f32x4 a0 = __builtin_amdgcn_mfma_f32_16x16x32_f16(Af[0][0], B0, accI[0], 0, 0, 0);
        f32x4 a1 = __builtin_amdgcn_mfma_f32_16x16x32_f16(Af[1][0], B0, accI[1], 0, 0, 0);
        a0 = __builtin_amdgcn_mfma_f32_16x16x32_f16(Af[0][1], B1, a0, 0, 0, 0);
        a1 = __builtin_amdgcn_mfma_f32_16x16x32_f16(Af[1][1], B1, a1, 0, 0, 0);

        // next-step acc init (independent; fills the pre-barrier shadow)
#pragma unroll
        for (int tt = 0; tt < 2; ++tt)
#pragma unroll
            for (int g = 0; g < 4; ++g)
                accI[tt][g] = xn * wih[tt][g] + bias[tt][g];

        // two cell chains PAIRED component-wise (x = cell0, y = cell1);
        // elementwise ops lower to v_pk_{add,mul,fma}_f32. (i,f,g,o pre-scaled)
        // A=e^-pi F=e^-pf B=e^-2pg C=e^-po
        // cc = [c(1+A)(1+B) + (1-B)(1+F)] / [(1+F)(1+A)(1+B)]
        // hn = (1-D)/[(1+C)(1+D)],  D = e^-2cc
        f32x2 eA, eF, eB, eC;
        eA.x = EXP2F(a0[0]); eA.y = EXP2F(a1[0]);
        eF.x = EXP2F(a0[1]); eF.y = EXP2F(a1[1]);
        eB.x = EXP2F(a0[2]); eB.y = EXP2F(a1[2]);
        eC.x = EXP2F(a0[3]); eC.y = EXP2F(a1[3]);

        const f32x2 pA = eA + 1.0f;
        const f32x2 pF = eF + 1.0f;
        const f32x2 pB = eB + 1.0f;
        const f32x2 pC = eC + 1.0f;
        const f32x2 P   = pA * pB;
        const f32x2 den = P * pF;
        const f32x2 tmb = (1.0f - eB) * pF;
        const f32x2 num = cst2 * P + tmb;
        f32x2 rden;
        rden.x = RCPF(den.x); rden.y = RCPF(den.y);
        const f32x2 cc = num * rden;
        cst2 = cc;
        f32x2 targ = cc * N2LOG2E;
        targ.x = MED3F(targ.x, -60.0f, 60.0f);   // avoid Inf/Inf -> NaN
        targ.y = MED3F(targ.y, -60.0f, 60.0f);
        f32x2 D;
        D.x = EXP2F(targ.x); D.y = EXP2F(targ.y);
        const f32x2 omD  = 1.0f - D;
        const f32x2 prod = pC * (1.0f + D);
        f32x2 rp;
        rp.x = RCPF(prod.x); rp.y = RCPF(prod.y);
        const f32x2 hn2 = omD * rp;

        // packed RNE fp16 pair -> one ds_write_b32 (consecutive units)
        *(unsigned*)&h_pl[p ^ 1][wo2] = pack2h(hn2.x, hn2.y);

        __syncthreads();
    };

#pragma unroll 1
    for (int t = 0; t < TT; t += 2) {
        stepf(0, t);       // reads buf0, writes buf1
        stepf(1, t + 1);   // reads buf1, writes buf0
    }
    // final h is in buffer 0

    // ---- tail: fc1 + relu into x_lds (x dead), then fc2 ----
    {
        const int b = tid >> 5, u2 = tid & 31;   // 512 = 16 x 32
        float a = fc1_b[u2];
        for (int k = 0; k < 64; ++k) {
            const int off = b * 64 + ((((k >> 3) ^ (b & 7))) << 3) + (k & 7);
            a += fc1_w[u2 * 64 + k] * h2f(h_pl[0][off]);
        }
        x_lds[b][u2] = a > 0.0f ? a : 0.0f;
    }
    __syncthreads();
    if (tid < BT * 2) {
        const int b = tid >> 1, o = tid & 1;
        float a = fc2_b[o];
#pragma unroll
        for (int u2 = 0; u2 < 32; ++u2)
            a += x_lds[b][u2] * fc2_w[o * 32 + u2];
        out[(bBase + b) * 2 + o] = a;
    }
}

extern "C" void kernel_launch(void* const* d_in, const int* in_sizes, int n_in,
                              void* d_out, int out_size, void* d_ws, size_t ws_size,
                              hipStream_t stream) {
    const float* x     = (const float*)d_in[0];
    const float* W_ih  = (const float*)d_in[1];
    const float* W_hh  = (const float*)d_in[2];
    const float* b_ih  = (const float*)d_in[3];
    const float* b_hh  = (const float*)d_in[4];
    const float* fc1_w = (const float*)d_in[5];
    const float* fc1_b = (const float*)d_in[6];
    const float* fc2_w = (const float*)d_in[7];
    const float* fc2_b = (const float*)d_in[8];
    float* out = (float*)d_out;

    lstm_pk<<<dim3(8192 / BT), dim3(512), 0, stream>>>(
        x, W_ih, W_hh, b_ih, b_hh, fc1_w, fc1_b, fc2_w, fc2_b, out);
}